// Round 1
// baseline (44.713 us; speedup 1.0000x reference)
//
#include <hip/hip_runtime.h>
#include <hip/hip_bf16.h>

#define IN_F   4096
#define OUT_F  11008
#define BATCH  32
#define GROUP  128

typedef __attribute__((ext_vector_type(8))) short  bf16x8;
typedef __attribute__((ext_vector_type(4))) float  f32x4;
typedef __attribute__((ext_vector_type(4))) int    i32x4;
typedef __attribute__((ext_vector_type(4))) float  float4v;

static __device__ __constant__ float NF4_LEVELS[16] = {
    -1.0f, -0.6961928009986877f, -0.5250730514526367f, -0.39491748809814453f,
    -0.28444138169288635f, -0.18477343022823334f, -0.09105003625154495f, 0.0f,
    0.07958029955625534f, 0.16093020141124725f, 0.24611230194568634f,
    0.33791524171829224f, 0.44070982933044434f, 0.5626170039176941f,
    0.7229568362236023f, 1.0f};

// ---------------------------------------------------------------------------
// Kernel 1: convert x (f32) -> bf16 into workspace
// ---------------------------------------------------------------------------
__global__ void cvt_x_kernel(const float* __restrict__ x,
                             __hip_bfloat16* __restrict__ xb, int n) {
    int i = (blockIdx.x * 256 + threadIdx.x) * 4;
    if (i + 3 < n) {
        float4v v = *reinterpret_cast<const float4v*>(x + i);
        __hip_bfloat16 h0 = __float2bfloat16(v.x);
        __hip_bfloat16 h1 = __float2bfloat16(v.y);
        __hip_bfloat16 h2 = __float2bfloat16(v.z);
        __hip_bfloat16 h3 = __float2bfloat16(v.w);
        ushort4 o;
        o.x = __builtin_bit_cast(unsigned short, h0);
        o.y = __builtin_bit_cast(unsigned short, h1);
        o.z = __builtin_bit_cast(unsigned short, h2);
        o.w = __builtin_bit_cast(unsigned short, h3);
        *reinterpret_cast<ushort4*>(reinterpret_cast<unsigned short*>(xb) + i) = o;
    }
}

// ---------------------------------------------------------------------------
// Kernel 2: NF4 dequant + GEMM via bf16 MFMA
//   grid = OUT_F/16 blocks, 256 threads (4 waves)
//   block handles 16 output features, full K=4096 split 4-ways across waves
// ---------------------------------------------------------------------------
__global__ __launch_bounds__(256) void nf4_gemm_kernel(
        const int*   __restrict__ packed,   // [OUT_F*IN_F/2], one byte per int32
        const float* __restrict__ scales,   // [OUT_F*IN_F/GROUP]
        const float* __restrict__ bias,     // [OUT_F]
        const __hip_bfloat16* __restrict__ xb,  // [BATCH][IN_F] bf16
        float* __restrict__ out)            // [BATCH][OUT_F]
{
    __shared__ float2 tab[256];              // byte -> (low-nibble level, high-nibble level)
    __shared__ float  red[4][2][16][16];     // per-wave partial tiles

    const int tid  = threadIdx.x;
    const int wave = tid >> 6;
    const int lane = tid & 63;
    const int col  = lane & 15;      // output-feature index within tile / batch row
    const int g    = lane >> 4;      // k-subgroup 0..3

    // build dequant table: entry v = (level(v&15), level(v>>4))
    {
        int v = tid;  // 256 threads exactly
        tab[v] = make_float2(NF4_LEVELS[v & 15], NF4_LEVELS[(v >> 4) & 15]);
    }
    __syncthreads();

    const int n0 = blockIdx.x * 16;
    const int o  = n0 + col;

    const int* prow = packed + (size_t)o * (IN_F / 2);
    const unsigned short* xs = reinterpret_cast<const unsigned short*>(xb);
    const unsigned short* xrow0 = xs + (size_t)col * IN_F;          // batch rows 0..15
    const unsigned short* xrow1 = xs + (size_t)(col + 16) * IN_F;   // batch rows 16..31

    const int kwave0 = wave * (IN_F / 4);   // 1024 per wave

    f32x4 acc0 = {0.f, 0.f, 0.f, 0.f};
    f32x4 acc1 = {0.f, 0.f, 0.f, 0.f};

    #pragma unroll
    for (int kg = 0; kg < 8; ++kg) {        // 8 scale-groups of 128 per wave
        const int kgrp = kwave0 + kg * GROUP;
        const float scale = scales[o * (IN_F / GROUP) + (kgrp >> 7)];
        #pragma unroll
        for (int s = 0; s < 4; ++s) {       // 4 MFMA k-steps of 32
            const int klane = kgrp + s * 32 + g * 8;   // this lane's 8 k-values
            // B fragment: 4 packed bytes -> 8 weights (k-contiguous)
            i32x4 p = *reinterpret_cast<const i32x4*>(prow + (klane >> 1));
            bf16x8 bfrag;
            #pragma unroll
            for (int j = 0; j < 4; ++j) {
                float2 lv = tab[p[j]];
                float w0 = lv.x * scale;
                float w1 = lv.y * scale;
                __hip_bfloat16 h0 = __float2bfloat16(w0);
                __hip_bfloat16 h1 = __float2bfloat16(w1);
                bfrag[2 * j]     = (short)__builtin_bit_cast(unsigned short, h0);
                bfrag[2 * j + 1] = (short)__builtin_bit_cast(unsigned short, h1);
            }
            // A fragments (two 16-row M tiles), same (lane,reg)->k map as B
            bf16x8 a0 = *reinterpret_cast<const bf16x8*>(xrow0 + klane);
            bf16x8 a1 = *reinterpret_cast<const bf16x8*>(xrow1 + klane);
            acc0 = __builtin_amdgcn_mfma_f32_16x16x32_bf16(a0, bfrag, acc0, 0, 0, 0);
            acc1 = __builtin_amdgcn_mfma_f32_16x16x32_bf16(a1, bfrag, acc1, 0, 0, 0);
        }
    }

    // cross-wave reduction: D layout row=(lane>>4)*4+j, col=lane&15
    #pragma unroll
    for (int j = 0; j < 4; ++j) {
        red[wave][0][g * 4 + j][col] = acc0[j];
        red[wave][1][g * 4 + j][col] = acc1[j];
    }
    __syncthreads();

    #pragma unroll
    for (int half = 0; half < 2; ++half) {
        int idx = half * 256 + tid;          // 0..511 outputs of this block
        int mt  = idx >> 8;                  // M tile
        int row = (idx >> 4) & 15;
        int c   = idx & 15;
        float ssum = red[0][mt][row][c] + red[1][mt][row][c] +
                     red[2][mt][row][c] + red[3][mt][row][c];
        int b  = mt * 16 + row;
        int oo = n0 + c;
        out[(size_t)b * OUT_F + oo] = ssum + bias[oo];
    }
}

// ---------------------------------------------------------------------------
extern "C" void kernel_launch(void* const* d_in, const int* in_sizes, int n_in,
                              void* d_out, int out_size, void* d_ws, size_t ws_size,
                              hipStream_t stream) {
    const float* x      = (const float*)d_in[0];
    const int*   packed = (const int*)d_in[1];
    const float* scales = (const float*)d_in[2];
    const float* bias   = (const float*)d_in[3];
    float* out = (float*)d_out;

    __hip_bfloat16* xb = (__hip_bfloat16*)d_ws;  // needs BATCH*IN_F*2 = 256 KB

    const int n = BATCH * IN_F;
    cvt_x_kernel<<<(n / 4 + 255) / 256, 256, 0, stream>>>(x, xb, n);
    nf4_gemm_kernel<<<OUT_F / 16, 256, 0, stream>>>(packed, scales, bias, xb, out);
}

// Round 2
// 43.368 us; speedup vs baseline: 1.0310x; 1.0310x over previous
//
#include <hip/hip_runtime.h>
#include <hip/hip_bf16.h>

#define IN_F   4096
#define OUT_F  11008
#define BATCH  32
#define GROUP  128
#define KSPLIT 4          // K split across blocks; each block covers 1024 k
#define KW     (IN_F / KSPLIT / 4)   // 256 k per wave

typedef __attribute__((ext_vector_type(8))) short  bf16x8;
typedef __attribute__((ext_vector_type(4))) float  f32x4;
typedef __attribute__((ext_vector_type(4))) int    i32x4;
typedef __attribute__((ext_vector_type(4))) float  float4v;

static __device__ __constant__ float NF4_LEVELS[16] = {
    -1.0f, -0.6961928009986877f, -0.5250730514526367f, -0.39491748809814453f,
    -0.28444138169288635f, -0.18477343022823334f, -0.09105003625154495f, 0.0f,
    0.07958029955625534f, 0.16093020141124725f, 0.24611230194568634f,
    0.33791524171829224f, 0.44070982933044434f, 0.5626170039176941f,
    0.7229568362236023f, 1.0f};

// ---------------------------------------------------------------------------
// Kernel 1: x f32->bf16 into ws, and out[b][o] = bias[o] (atomic targets)
//   grid: 344 blocks x 256 = 88064 threads; out has 352256 = 88064*4 elems
// ---------------------------------------------------------------------------
__global__ void prelude_kernel(const float* __restrict__ x,
                               __hip_bfloat16* __restrict__ xb,
                               const float* __restrict__ bias,
                               float* __restrict__ out) {
    int t = blockIdx.x * 256 + threadIdx.x;
    if (t < (BATCH * IN_F / 4)) {
        int i = t * 4;
        float4v v = *reinterpret_cast<const float4v*>(x + i);
        ushort4 o;
        o.x = __builtin_bit_cast(unsigned short, __float2bfloat16(v.x));
        o.y = __builtin_bit_cast(unsigned short, __float2bfloat16(v.y));
        o.z = __builtin_bit_cast(unsigned short, __float2bfloat16(v.z));
        o.w = __builtin_bit_cast(unsigned short, __float2bfloat16(v.w));
        *reinterpret_cast<ushort4*>(reinterpret_cast<unsigned short*>(xb) + i) = o;
    }
    // out init with bias (OUT_F % 4 == 0 so o-pattern aligns with float4)
    int i = t * 4;
    int o = i % OUT_F;
    float4v b = *reinterpret_cast<const float4v*>(bias + o);
    *reinterpret_cast<float4v*>(out + i) = b;
}

// ---------------------------------------------------------------------------
// Kernel 2: NF4 dequant + GEMM via bf16 MFMA, K-split with atomic accumulate
//   grid = (OUT_F/16, KSPLIT), 256 threads (4 waves)
// ---------------------------------------------------------------------------
__global__ __launch_bounds__(256) void nf4_gemm_kernel(
        const int*   __restrict__ packed,   // [OUT_F*IN_F/2], one byte per int32
        const float* __restrict__ scales,   // [OUT_F*IN_F/GROUP]
        const __hip_bfloat16* __restrict__ xb,  // [BATCH][IN_F] bf16
        float* __restrict__ out)            // [BATCH][OUT_F], bias-initialized
{
    __shared__ float2 tab[256];              // byte -> (low nibble, high nibble) levels
    __shared__ float  red[4][2][16][16];     // per-wave partial tiles

    const int tid  = threadIdx.x;
    const int wave = tid >> 6;
    const int lane = tid & 63;
    const int col  = lane & 15;      // output feature within tile / batch row
    const int g    = lane >> 4;      // k-subgroup 0..3

    tab[tid] = make_float2(NF4_LEVELS[tid & 15], NF4_LEVELS[(tid >> 4) & 15]);
    __syncthreads();

    const int n0 = blockIdx.x * 16;
    const int o  = n0 + col;

    const int* prow = packed + (size_t)o * (IN_F / 2);
    const unsigned short* xs = reinterpret_cast<const unsigned short*>(xb);
    const unsigned short* xrow0 = xs + (size_t)col * IN_F;          // batch 0..15
    const unsigned short* xrow1 = xs + (size_t)(col + 16) * IN_F;   // batch 16..31

    const int kwave0 = blockIdx.y * (IN_F / KSPLIT) + wave * KW;    // 256 k per wave

    // ---- issue ALL packed loads for this wave up front (8 x 16B in flight) ----
    i32x4 p[2][4];
    float scale[2];
    #pragma unroll
    for (int kg = 0; kg < 2; ++kg) {
        const int kgrp = kwave0 + kg * GROUP;
        #pragma unroll
        for (int s = 0; s < 4; ++s) {
            const int klane = kgrp + s * 32 + g * 8;
            p[kg][s] = *reinterpret_cast<const i32x4*>(prow + (klane >> 1));
        }
    }
    #pragma unroll
    for (int kg = 0; kg < 2; ++kg)
        scale[kg] = scales[o * (IN_F / GROUP) + ((kwave0 + kg * GROUP) >> 7)];

    f32x4 acc0 = {0.f, 0.f, 0.f, 0.f};
    f32x4 acc1 = {0.f, 0.f, 0.f, 0.f};

    #pragma unroll
    for (int kg = 0; kg < 2; ++kg) {
        #pragma unroll
        for (int s = 0; s < 4; ++s) {
            const int klane = kwave0 + kg * GROUP + s * 32 + g * 8;
            bf16x8 bfrag;
            #pragma unroll
            for (int j = 0; j < 4; ++j) {
                float2 lv = tab[p[kg][s][j]];
                bfrag[2 * j] = (short)__builtin_bit_cast(unsigned short,
                                  __float2bfloat16(lv.x * scale[kg]));
                bfrag[2 * j + 1] = (short)__builtin_bit_cast(unsigned short,
                                  __float2bfloat16(lv.y * scale[kg]));
            }
            bf16x8 a0 = *reinterpret_cast<const bf16x8*>(xrow0 + klane);
            bf16x8 a1 = *reinterpret_cast<const bf16x8*>(xrow1 + klane);
            acc0 = __builtin_amdgcn_mfma_f32_16x16x32_bf16(a0, bfrag, acc0, 0, 0, 0);
            acc1 = __builtin_amdgcn_mfma_f32_16x16x32_bf16(a1, bfrag, acc1, 0, 0, 0);
        }
    }

    // cross-wave reduction: D layout row=(lane>>4)*4+j, col=lane&15
    #pragma unroll
    for (int j = 0; j < 4; ++j) {
        red[wave][0][g * 4 + j][col] = acc0[j];
        red[wave][1][g * 4 + j][col] = acc1[j];
    }
    __syncthreads();

    #pragma unroll
    for (int half = 0; half < 2; ++half) {
        int idx = half * 256 + tid;          // 0..511 outputs of this block
        int mt  = idx >> 8;
        int row = (idx >> 4) & 15;
        int c   = idx & 15;
        float ssum = red[0][mt][row][c] + red[1][mt][row][c] +
                     red[2][mt][row][c] + red[3][mt][row][c];
        int b  = mt * 16 + row;
        unsafeAtomicAdd(out + (size_t)b * OUT_F + (n0 + c), ssum);
    }
}

// ---------------------------------------------------------------------------
extern "C" void kernel_launch(void* const* d_in, const int* in_sizes, int n_in,
                              void* d_out, int out_size, void* d_ws, size_t ws_size,
                              hipStream_t stream) {
    const float* x      = (const float*)d_in[0];
    const int*   packed = (const int*)d_in[1];
    const float* scales = (const float*)d_in[2];
    const float* bias   = (const float*)d_in[3];
    float* out = (float*)d_out;

    __hip_bfloat16* xb = (__hip_bfloat16*)d_ws;  // BATCH*IN_F*2 = 256 KB

    prelude_kernel<<<(BATCH * OUT_F / 4 + 255) / 256, 256, 0, stream>>>(x, xb, bias, out);
    dim3 grid(OUT_F / 16, KSPLIT);
    nf4_gemm_kernel<<<grid, 256, 0, stream>>>(packed, scales, xb, out);
}

// Round 3
// 38.840 us; speedup vs baseline: 1.1512x; 1.1166x over previous
//
#include <hip/hip_runtime.h>
#include <hip/hip_bf16.h>

#define IN_F   4096
#define OUT_F  11008
#define BATCH  32
#define GROUP  128
#define KSPLIT 8
#define KBLK   (IN_F / KSPLIT)      // 512 k per block
#define NSTEPS (KBLK / 32)          // 16 MFMA k-steps

typedef __attribute__((ext_vector_type(8))) short  bf16x8;
typedef __attribute__((ext_vector_type(4))) float  f32x4;
typedef __attribute__((ext_vector_type(4))) int    i32x4;
typedef __attribute__((ext_vector_type(4))) float  float4v;

static __device__ __constant__ float NF4_LEVELS[16] = {
    -1.0f, -0.6961928009986877f, -0.5250730514526367f, -0.39491748809814453f,
    -0.28444138169288635f, -0.18477343022823334f, -0.09105003625154495f, 0.0f,
    0.07958029955625534f, 0.16093020141124725f, 0.24611230194568634f,
    0.33791524171829224f, 0.44070982933044434f, 0.5626170039176941f,
    0.7229568362236023f, 1.0f};

// ---------------------------------------------------------------------------
// Kernel 1: x f32->bf16 into ws; out[b][o] = bias[o] (atomic accumulate base)
// ---------------------------------------------------------------------------
__global__ void prelude_kernel(const float* __restrict__ x,
                               __hip_bfloat16* __restrict__ xb,
                               const float* __restrict__ bias,
                               float* __restrict__ out) {
    int t = blockIdx.x * 256 + threadIdx.x;
    if (t < (BATCH * IN_F / 4)) {
        int i = t * 4;
        float4v v = *reinterpret_cast<const float4v*>(x + i);
        ushort4 o;
        o.x = __builtin_bit_cast(unsigned short, __float2bfloat16(v.x));
        o.y = __builtin_bit_cast(unsigned short, __float2bfloat16(v.y));
        o.z = __builtin_bit_cast(unsigned short, __float2bfloat16(v.z));
        o.w = __builtin_bit_cast(unsigned short, __float2bfloat16(v.w));
        *reinterpret_cast<ushort4*>(reinterpret_cast<unsigned short*>(xb) + i) = o;
    }
    int i = t * 4;
    int o = i % OUT_F;               // OUT_F % 4 == 0, stays aligned
    float4v b = *reinterpret_cast<const float4v*>(bias + o);
    *reinterpret_cast<float4v*>(out + i) = b;
}

// ---------------------------------------------------------------------------
// Kernel 2: NF4 dequant + GEMM, software-pipelined.
//   grid = (OUT_F/128, KSPLIT), 256 threads (4 waves).
//   Wave w owns out-rows [blockIdx.x*128 + w*32, +32) x K-range [by*512, +512).
//   Two 16-row B strips per wave; M=32 as two 16-row A tiles; 4 MFMA / k-step.
// ---------------------------------------------------------------------------
__global__ __launch_bounds__(256) void nf4_gemm_kernel(
        const int*   __restrict__ packed,   // [OUT_F*IN_F/2] one byte per int32
        const float* __restrict__ scales,   // [OUT_F*IN_F/GROUP]
        const __hip_bfloat16* __restrict__ xb,  // [BATCH][IN_F] bf16
        float* __restrict__ out)            // [BATCH][OUT_F], bias-initialized
{
    __shared__ float2 tab[256];   // byte -> (low-nibble level, high-nibble level)

    const int tid  = threadIdx.x;
    const int wave = tid >> 6;
    const int lane = tid & 63;
    const int col  = lane & 15;          // row-within-strip (B) / batch row (A)
    const int g    = lane >> 4;          // k subgroup 0..3

    tab[tid] = make_float2(NF4_LEVELS[tid & 15], NF4_LEVELS[(tid >> 4) & 15]);
    __syncthreads();

    const int nbase = blockIdx.x * 128 + wave * 32;
    const int oA = nbase + col;          // strip A out-row
    const int oB = nbase + 16 + col;     // strip B out-row
    const int k0 = blockIdx.y * KBLK;
    const int kl = k0 + g * 8;           // this lane's k base

    const int* prowA = packed + (size_t)oA * (IN_F / 2);
    const int* prowB = packed + (size_t)oB * (IN_F / 2);
    const unsigned short* xs  = reinterpret_cast<const unsigned short*>(xb);
    const unsigned short* xr0 = xs + (size_t)col * IN_F;          // batch 0..15
    const unsigned short* xr1 = xs + (size_t)(col + 16) * IN_F;   // batch 16..31

    // scales for the 4 groups in this K range (prefetched, no stalls later)
    float scA[4], scB[4];
    #pragma unroll
    for (int i = 0; i < 4; ++i) {
        scA[i] = scales[oA * (IN_F / GROUP) + (k0 >> 7) + i];
        scB[i] = scales[oB * (IN_F / GROUP) + (k0 >> 7) + i];
    }

    f32x4 acc00 = {0.f,0.f,0.f,0.f};   // batch 0-15  x strip A
    f32x4 acc10 = {0.f,0.f,0.f,0.f};   // batch 16-31 x strip A
    f32x4 acc01 = {0.f,0.f,0.f,0.f};   // batch 0-15  x strip B
    f32x4 acc11 = {0.f,0.f,0.f,0.f};   // batch 16-31 x strip B

    // ---- software pipeline: packed depth 3, A-frags depth 2 ----
    i32x4  pA[3], pB[3];
    bf16x8 a0[2], a1[2];
    #pragma unroll
    for (int s = 0; s < 3; ++s) {
        pA[s] = *reinterpret_cast<const i32x4*>(prowA + ((kl + s * 32) >> 1));
        pB[s] = *reinterpret_cast<const i32x4*>(prowB + ((kl + s * 32) >> 1));
    }
    #pragma unroll
    for (int s = 0; s < 2; ++s) {
        a0[s] = *reinterpret_cast<const bf16x8*>(xr0 + kl + s * 32);
        a1[s] = *reinterpret_cast<const bf16x8*>(xr1 + kl + s * 32);
    }

    #pragma unroll
    for (int s = 0; s < NSTEPS; ++s) {
        // issue next prefetches FIRST (independent of this step's compute)
        i32x4  npA = {}, npB = {};
        bf16x8 na0 = {}, na1 = {};
        if (s + 3 < NSTEPS) {
            npA = *reinterpret_cast<const i32x4*>(prowA + ((kl + (s + 3) * 32) >> 1));
            npB = *reinterpret_cast<const i32x4*>(prowB + ((kl + (s + 3) * 32) >> 1));
        }
        if (s + 2 < NSTEPS) {
            na0 = *reinterpret_cast<const bf16x8*>(xr0 + kl + (s + 2) * 32);
            na1 = *reinterpret_cast<const bf16x8*>(xr1 + kl + (s + 2) * 32);
        }

        const float sA = scA[s >> 2];
        const float sB = scB[s >> 2];
        bf16x8 bA, bB;
        #pragma unroll
        for (int j = 0; j < 4; ++j) {
            float2 lvA = tab[pA[s % 3][j]];
            float2 lvB = tab[pB[s % 3][j]];
            bA[2*j]   = (short)__builtin_bit_cast(unsigned short, __float2bfloat16(lvA.x * sA));
            bA[2*j+1] = (short)__builtin_bit_cast(unsigned short, __float2bfloat16(lvA.y * sA));
            bB[2*j]   = (short)__builtin_bit_cast(unsigned short, __float2bfloat16(lvB.x * sB));
            bB[2*j+1] = (short)__builtin_bit_cast(unsigned short, __float2bfloat16(lvB.y * sB));
        }
        acc00 = __builtin_amdgcn_mfma_f32_16x16x32_bf16(a0[s % 2], bA, acc00, 0, 0, 0);
        acc10 = __builtin_amdgcn_mfma_f32_16x16x32_bf16(a1[s % 2], bA, acc10, 0, 0, 0);
        acc01 = __builtin_amdgcn_mfma_f32_16x16x32_bf16(a0[s % 2], bB, acc01, 0, 0, 0);
        acc11 = __builtin_amdgcn_mfma_f32_16x16x32_bf16(a1[s % 2], bB, acc11, 0, 0, 0);

        if (s + 3 < NSTEPS) { pA[s % 3] = npA; pB[s % 3] = npB; }
        if (s + 2 < NSTEPS) { a0[s % 2] = na0; a1[s % 2] = na1; }
    }

    // epilogue: D layout row=(lane>>4)*4+j (batch), col=lane&15 (out feature)
    #pragma unroll
    for (int j = 0; j < 4; ++j) {
        int b0 = g * 4 + j;
        unsafeAtomicAdd(out + (size_t)b0 * OUT_F + oA, acc00[j]);
        unsafeAtomicAdd(out + (size_t)(b0 + 16) * OUT_F + oA, acc10[j]);
        unsafeAtomicAdd(out + (size_t)b0 * OUT_F + oB, acc01[j]);
        unsafeAtomicAdd(out + (size_t)(b0 + 16) * OUT_F + oB, acc11[j]);
    }
}

// ---------------------------------------------------------------------------
extern "C" void kernel_launch(void* const* d_in, const int* in_sizes, int n_in,
                              void* d_out, int out_size, void* d_ws, size_t ws_size,
                              hipStream_t stream) {
    const float* x      = (const float*)d_in[0];
    const int*   packed = (const int*)d_in[1];
    const float* scales = (const float*)d_in[2];
    const float* bias   = (const float*)d_in[3];
    float* out = (float*)d_out;

    __hip_bfloat16* xb = (__hip_bfloat16*)d_ws;  // BATCH*IN_F*2 = 256 KB

    prelude_kernel<<<(BATCH * OUT_F / 4 + 255) / 256, 256, 0, stream>>>(x, xb, bias, out);
    dim3 grid(OUT_F / 128, KSPLIT);
    nf4_gemm_kernel<<<grid, 256, 0, stream>>>(packed, scales, xb, out);
}

// Round 4
// 37.698 us; speedup vs baseline: 1.1861x; 1.0303x over previous
//
#include <hip/hip_runtime.h>
#include <hip/hip_bf16.h>

#define IN_F   4096
#define OUT_F  11008
#define BATCH  32
#define GROUP  128
#define KSPLIT 8
#define KBLK   (IN_F / KSPLIT)      // 512 k per block
#define NSTEPS (KBLK / 32)          // 16 MFMA k-steps (4 scale-groups of 4)

typedef __attribute__((ext_vector_type(8))) short  bf16x8;
typedef __attribute__((ext_vector_type(4))) float  f32x4;
typedef __attribute__((ext_vector_type(4))) int    i32x4;
typedef __attribute__((ext_vector_type(4))) float  float4v;

static __device__ __constant__ float NF4_LEVELS[16] = {
    -1.0f, -0.6961928009986877f, -0.5250730514526367f, -0.39491748809814453f,
    -0.28444138169288635f, -0.18477343022823334f, -0.09105003625154495f, 0.0f,
    0.07958029955625534f, 0.16093020141124725f, 0.24611230194568634f,
    0.33791524171829224f, 0.44070982933044434f, 0.5626170039176941f,
    0.7229568362236023f, 1.0f};

// ---------------------------------------------------------------------------
// Kernel 1: x f32->bf16 into ws; out[b][o] = bias[o] (atomic accumulate base)
// ---------------------------------------------------------------------------
__global__ void prelude_kernel(const float* __restrict__ x,
                               __hip_bfloat16* __restrict__ xb,
                               const float* __restrict__ bias,
                               float* __restrict__ out) {
    int t = blockIdx.x * 256 + threadIdx.x;
    if (t < (BATCH * IN_F / 4)) {
        int i = t * 4;
        float4v v = *reinterpret_cast<const float4v*>(x + i);
        ushort4 o;
        o.x = __builtin_bit_cast(unsigned short, __float2bfloat16(v.x));
        o.y = __builtin_bit_cast(unsigned short, __float2bfloat16(v.y));
        o.z = __builtin_bit_cast(unsigned short, __float2bfloat16(v.z));
        o.w = __builtin_bit_cast(unsigned short, __float2bfloat16(v.w));
        *reinterpret_cast<ushort4*>(reinterpret_cast<unsigned short*>(xb) + i) = o;
    }
    int i = t * 4;
    int o = i % OUT_F;               // OUT_F % 4 == 0, stays aligned
    float4v b = *reinterpret_cast<const float4v*>(bias + o);
    *reinterpret_cast<float4v*>(out + i) = b;
}

// ---------------------------------------------------------------------------
// Kernel 2: NF4 dequant + GEMM.
//   Table holds PRE-PACKED bf16 level pairs -> B fragment = 4 ds_read_b32,
//   no VALU dequant. Group scale folded out: unscaled MFMA partials per
//   128-k group, then acc += scale * partial (valid: every C elem of a lane
//   has col = lane&15 = same out-row => same scale).
//   grid = (OUT_F/128, KSPLIT), 256 threads (4 waves), wave owns 32 out-rows.
// ---------------------------------------------------------------------------
__global__ __launch_bounds__(256) void nf4_gemm_kernel(
        const int*   __restrict__ packed,   // [OUT_F*IN_F/2] one byte per int32
        const float* __restrict__ scales,   // [OUT_F*IN_F/GROUP]
        const __hip_bfloat16* __restrict__ xb,  // [BATCH][IN_F] bf16
        float* __restrict__ out)            // [BATCH][OUT_F], bias-initialized
{
    __shared__ unsigned int tabu[256];   // byte -> bf16(level_lo) | bf16(level_hi)<<16

    const int tid  = threadIdx.x;
    const int wave = tid >> 6;
    const int lane = tid & 63;
    const int col  = lane & 15;          // out-row within strip / batch row
    const int g    = lane >> 4;          // k subgroup 0..3

    {
        unsigned lo = __builtin_bit_cast(unsigned short, __float2bfloat16(NF4_LEVELS[tid & 15]));
        unsigned hi = __builtin_bit_cast(unsigned short, __float2bfloat16(NF4_LEVELS[(tid >> 4) & 15]));
        tabu[tid] = lo | (hi << 16);
    }
    __syncthreads();

    const int nbase = blockIdx.x * 128 + wave * 32;
    const int oA = nbase + col;          // strip A out-row
    const int oB = nbase + 16 + col;     // strip B out-row
    const int k0 = blockIdx.y * KBLK;
    const int kl = k0 + g * 8;           // this lane's k base

    const int* prowA = packed + (size_t)oA * (IN_F / 2);
    const int* prowB = packed + (size_t)oB * (IN_F / 2);
    const unsigned short* xs  = reinterpret_cast<const unsigned short*>(xb);
    const unsigned short* xr0 = xs + (size_t)col * IN_F;          // batch 0..15
    const unsigned short* xr1 = xs + (size_t)(col + 16) * IN_F;   // batch 16..31

    float scA[4], scB[4];
    #pragma unroll
    for (int i = 0; i < 4; ++i) {
        scA[i] = scales[oA * (IN_F / GROUP) + (k0 >> 7) + i];
        scB[i] = scales[oB * (IN_F / GROUP) + (k0 >> 7) + i];
    }

    f32x4 acc00 = {0.f,0.f,0.f,0.f};   // batch 0-15  x strip A
    f32x4 acc10 = {0.f,0.f,0.f,0.f};   // batch 16-31 x strip A
    f32x4 acc01 = {0.f,0.f,0.f,0.f};   // batch 0-15  x strip B
    f32x4 acc11 = {0.f,0.f,0.f,0.f};   // batch 16-31 x strip B

    // ---- software pipeline: packed depth 3, A-frags depth 2 ----
    i32x4  pA[3], pB[3];
    bf16x8 a0[2], a1[2];
    #pragma unroll
    for (int s = 0; s < 3; ++s) {
        pA[s] = *reinterpret_cast<const i32x4*>(prowA + ((kl + s * 32) >> 1));
        pB[s] = *reinterpret_cast<const i32x4*>(prowB + ((kl + s * 32) >> 1));
    }
    #pragma unroll
    for (int s = 0; s < 2; ++s) {
        a0[s] = *reinterpret_cast<const bf16x8*>(xr0 + kl + s * 32);
        a1[s] = *reinterpret_cast<const bf16x8*>(xr1 + kl + s * 32);
    }

    #pragma unroll
    for (int g4 = 0; g4 < 4; ++g4) {               // 4 scale-groups of 128 k
        f32x4 t00 = {0.f,0.f,0.f,0.f};
        f32x4 t10 = {0.f,0.f,0.f,0.f};
        f32x4 t01 = {0.f,0.f,0.f,0.f};
        f32x4 t11 = {0.f,0.f,0.f,0.f};
        #pragma unroll
        for (int s4 = 0; s4 < 4; ++s4) {
            const int s = g4 * 4 + s4;             // compile-time constant
            i32x4  npA = {}, npB = {};
            bf16x8 na0 = {}, na1 = {};
            if (s + 3 < NSTEPS) {
                npA = *reinterpret_cast<const i32x4*>(prowA + ((kl + (s + 3) * 32) >> 1));
                npB = *reinterpret_cast<const i32x4*>(prowB + ((kl + (s + 3) * 32) >> 1));
            }
            if (s + 2 < NSTEPS) {
                na0 = *reinterpret_cast<const bf16x8*>(xr0 + kl + (s + 2) * 32);
                na1 = *reinterpret_cast<const bf16x8*>(xr1 + kl + (s + 2) * 32);
            }

            // B fragments: pure table reads of pre-packed bf16 pairs
            i32x4 bAu, bBu;
            #pragma unroll
            for (int j = 0; j < 4; ++j) {
                bAu[j] = (int)tabu[((unsigned)pA[s % 3][j]) & 255u];
                bBu[j] = (int)tabu[((unsigned)pB[s % 3][j]) & 255u];
            }
            bf16x8 bA = __builtin_bit_cast(bf16x8, bAu);
            bf16x8 bB = __builtin_bit_cast(bf16x8, bBu);

            t00 = __builtin_amdgcn_mfma_f32_16x16x32_bf16(a0[s % 2], bA, t00, 0, 0, 0);
            t10 = __builtin_amdgcn_mfma_f32_16x16x32_bf16(a1[s % 2], bA, t10, 0, 0, 0);
            t01 = __builtin_amdgcn_mfma_f32_16x16x32_bf16(a0[s % 2], bB, t01, 0, 0, 0);
            t11 = __builtin_amdgcn_mfma_f32_16x16x32_bf16(a1[s % 2], bB, t11, 0, 0, 0);

            if (s + 3 < NSTEPS) { pA[s % 3] = npA; pB[s % 3] = npB; }
            if (s + 2 < NSTEPS) { a0[s % 2] = na0; a1[s % 2] = na1; }
        }
        // fold the group scale in once per 128-k group
        #pragma unroll
        for (int j = 0; j < 4; ++j) {
            acc00[j] = fmaf(scA[g4], t00[j], acc00[j]);
            acc10[j] = fmaf(scA[g4], t10[j], acc10[j]);
            acc01[j] = fmaf(scB[g4], t01[j], acc01[j]);
            acc11[j] = fmaf(scB[g4], t11[j], acc11[j]);
        }
    }

    // epilogue: D layout row=(lane>>4)*4+j (batch), col=lane&15 (out feature)
    #pragma unroll
    for (int j = 0; j < 4; ++j) {
        int b0 = g * 4 + j;
        unsafeAtomicAdd(out + (size_t)b0 * OUT_F + oA, acc00[j]);
        unsafeAtomicAdd(out + (size_t)(b0 + 16) * OUT_F + oA, acc10[j]);
        unsafeAtomicAdd(out + (size_t)b0 * OUT_F + oB, acc01[j]);
        unsafeAtomicAdd(out + (size_t)(b0 + 16) * OUT_F + oB, acc11[j]);
    }
}

// ---------------------------------------------------------------------------
extern "C" void kernel_launch(void* const* d_in, const int* in_sizes, int n_in,
                              void* d_out, int out_size, void* d_ws, size_t ws_size,
                              hipStream_t stream) {
    const float* x      = (const float*)d_in[0];
    const int*   packed = (const int*)d_in[1];
    const float* scales = (const float*)d_in[2];
    const float* bias   = (const float*)d_in[3];
    float* out = (float*)d_out;

    __hip_bfloat16* xb = (__hip_bfloat16*)d_ws;  // BATCH*IN_F*2 = 256 KB

    prelude_kernel<<<(BATCH * OUT_F / 4 + 255) / 256, 256, 0, stream>>>(x, xb, bias, out);
    dim3 grid(OUT_F / 128, KSPLIT);
    nf4_gemm_kernel<<<grid, 256, 0, stream>>>(packed, scales, xb, out);
}